// Round 13
// baseline (7120.704 us; speedup 1.0000x reference)
//
#include <hip/hip_runtime.h>
#include <hip/hip_bf16.h>

typedef __attribute__((ext_vector_type(8))) __bf16 bf16x8;
typedef __attribute__((ext_vector_type(4))) float f32x4;

static constexpr int BB = 64;    // batch
static constexpr int SS = 512;   // seq len
static constexpr int IN = 512;   // input dim
static constexpr int HH = 1024;  // hidden
static constexpr int OO = 512;   // output dim
static constexpr int KK = 1536;  // H + I (combined recurrent K)
static constexpr int G4 = 4096;  // 4*H
static constexpr int NBLK = 256; // recurrent blocks (1 per CU)
static constexpr int COLS = 16;  // gate-cols per recurrent block (G4/NBLK)
static constexpr int HCPB = 4;   // h-cols per recurrent block (HH/NBLK)

__device__ __forceinline__ f32x4 mfma16(bf16x8 a, bf16x8 b, f32x4 c) {
  return __builtin_amdgcn_mfma_f32_16x16x32_bf16(a, b, c, 0, 0, 0);
}
__device__ __forceinline__ float sigm(float x) { return 1.f / (1.f + __expf(-x)); }
__device__ __forceinline__ float tanh_f(float x) { return 1.f - 2.f / (1.f + __expf(2.f * x)); }

// Gate-col permutation: p = n*16 + g*4 + r  <->  gate g, hcol = n*4 + r.

__global__ void k_convw(const float* Wf, const float* Wi, const float* Wo, const float* Wc,
                        const float* bfv, const float* biv, const float* bov, const float* bcv,
                        __bf16* Wcomb, float* biasp) {
  int p = blockIdx.x;                       // 0..4095
  int g = (p >> 2) & 3;
  int hcol = ((p >> 4) << 2) | (p & 3);
  const float* Wg = (g == 0) ? Wf : (g == 1) ? Wi : (g == 2) ? Wo : Wc;
  const float* bg = (g == 0) ? bfv : (g == 1) ? biv : (g == 2) ? bov : bcv;
  const float* src = Wg + (size_t)hcol * KK;
  for (int k = threadIdx.x; k < KK; k += 256) Wcomb[(size_t)p * KK + k] = (__bf16)src[k];
  if (threadIdx.x == 0) biasp[p] = bg[hcol];
}

// xb[(t*64+b)*512 + k] = bf16(x[b][t][k])   (t-major rows for the recurrent A-fragments)
__global__ void k_convx(const float* x, __bf16* xb) {
  size_t idx = (size_t)blockIdx.x * 256 + threadIdx.x;  // 16,777,216
  int k = idx & 511;
  size_t row = idx >> 9;
  int t = (int)(row >> 6), b = (int)(row & 63);
  xb[idx] = (__bf16)x[((size_t)b * SS + t) * IN + k];
}

__global__ void k_convfc(const float* Wfc, __bf16* Wfcb) {
  size_t i = (size_t)blockIdx.x * 256 + threadIdx.x;  // 524,288
  Wfcb[i] = (__bf16)Wfc[i];
}

__global__ void k_zeroh0(__bf16* hsb) {
  size_t i = (size_t)blockIdx.x * 256 + threadIdx.x;  // 65,536 (slot 0 = h_{-1} = 0)
  hsb[i] = (__bf16)0.f;
}

__global__ void k_diag(float* out, float v) { out[0] = v; }

// Persistent recurrent kernel: 256 blocks x 256 thr. DECOUPLED WAVE-GROUPS:
// batch rows split 4x16 across waves; group g (wave g of every block) is an
// INDEPENDENT recurrence over rows 16g..16g+15 (it reads only those h rows and
// produces only those). Per-wave flag array flags[w*256+n], per-wave 64-lane
// poll, per-wave vmcnt drain + flag write. ZERO in-loop barriers: each wave's
// period = fabric RT + its own work; no intra-block straggler coupling; the 4
// groups self-offset in time, smoothing the h-broadcast bursts on L2/LLC.
__global__ __launch_bounds__(256) void k_lstm(const __bf16* __restrict__ Wcomb,
                                              const __bf16* __restrict__ xb,
                                              const float* __restrict__ biasp,
                                              __bf16* __restrict__ hsb,
                                              float* __restrict__ tail,
                                              unsigned* __restrict__ flags) {
  const int n = blockIdx.x;
  const int tid = threadIdx.x;
  const int w = tid >> 6, l = tid & 63;
  const int l16 = l & 15, lk = l >> 4;
  __shared__ __bf16 wl[48 * 512];   // 48 chunks x (4 lk x 16 cols x 8) bf16 = 49,152 B
  __shared__ float gt[4][16][20];   // per-wave D spill: [wave][row-in-group][col], 2-way banks
  // --- preload weight slice into LDS, fragment-major ---
  for (int i = tid; i < COLS * (KK / 8); i += 256) {  // 16*192 = 3072
    int c = i / 192, kch = i % 192;
    bf16x8 v = *(const bf16x8*)(Wcomb + ((size_t)(n * COLS + c)) * KK + kch * 8);
    int chunk = kch >> 2, lkw = kch & 3;
    *(bf16x8*)(wl + ((chunk * 64 + lkw * 16 + c) << 3)) = v;
  }
  const int br2 = l >> 2, rr = l & 3;     // act mapping inside the group: row 0..15, hcol-off
  const int absrow = w * 16 + br2;        // global batch row (== old tid>>2)
  const float bias_f = biasp[n * COLS + 0 + rr];
  const float bias_i = biasp[n * COLS + 4 + rr];
  const float bias_o = biasp[n * COLS + 8 + rr];
  const float bias_c = biasp[n * COLS + 12 + rr];
  __syncthreads();  // weights staged — the ONLY block barrier in the kernel
  const size_t aoffH = (size_t)(w * 16 + l16) * HH + lk * 8;
  const size_t aoffX = (size_t)(w * 16 + l16) * IN + lk * 8;
  const __bf16* wlane = wl + ((lk * 16 + l16) << 3);
  unsigned* myflags = flags + w * 256;    // this group's 256 producer flags
  const int startC = (n >> 3) & 15;       // stagger key: co-XCD siblings differ
  const f32x4 vz = {0.f, 0.f, 0.f, 0.f};
  float cst = 0.f;
  for (int t = 0; t < SS; ++t) {
    const __bf16* hp = hsb + (size_t)t * (BB * HH);
    const __bf16* xp = xb + (size_t)t * (BB * IN);
    f32x4 a0 = vz, a1 = vz;
    // ---- phase A: x-part (no h dependency; runs during other producers' tail) ----
#pragma unroll
    for (int kc = 0; kc < IN; kc += 64) {   // x-part: chunks 32..47
      bf16x8 av0 = *(const bf16x8*)(xp + aoffX + kc);
      bf16x8 av1 = *(const bf16x8*)(xp + aoffX + kc + 32);
      bf16x8 bv0 = *(const bf16x8*)(wlane + (32 + kc / 32) * 512);
      bf16x8 bv1 = *(const bf16x8*)(wlane + (33 + kc / 32) * 512);
      a0 = mfma16(av0, bv0, a0);
      a1 = mfma16(av1, bv1, a1);
    }
    // ---- phase B: per-wave wait for THIS GROUP's 256 producers (64-lane poll) ----
    {
      const unsigned tgt = (unsigned)t;
      for (;;) {
        unsigned f0 = __hip_atomic_load(&myflags[l * 4 + 0], __ATOMIC_RELAXED, __HIP_MEMORY_SCOPE_AGENT);
        unsigned f1 = __hip_atomic_load(&myflags[l * 4 + 1], __ATOMIC_RELAXED, __HIP_MEMORY_SCOPE_AGENT);
        unsigned f2 = __hip_atomic_load(&myflags[l * 4 + 2], __ATOMIC_RELAXED, __HIP_MEMORY_SCOPE_AGENT);
        unsigned f3 = __hip_atomic_load(&myflags[l * 4 + 3], __ATOMIC_RELAXED, __HIP_MEMORY_SCOPE_AGENT);
        bool ok = (f0 >= tgt) & (f1 >= tgt) & (f2 >= tgt) & (f3 >= tgt);
        if (__all((int)ok)) break;
        __builtin_amdgcn_s_sleep(1);
      }
    }
    asm volatile("" ::: "memory");  // no speculative h-load hoisting above the wait
    // ---- phase C: h-part (this group's 16 rows only; plain cached loads) ----
#pragma unroll
    for (int i = 0; i < 16; ++i) {
      int cc = (startC + i) & 15;       // 16 double-chunks of 64 k each
      int kc = cc * 64;
      bf16x8 av0 = *(const bf16x8*)(hp + aoffH + kc);
      bf16x8 av1 = *(const bf16x8*)(hp + aoffH + kc + 32);
      bf16x8 bv0 = *(const bf16x8*)(wlane + (cc * 2) * 512);
      bf16x8 bv1 = *(const bf16x8*)(wlane + (cc * 2 + 1) * 512);
      a0 = mfma16(av0, bv0, a0);
      a1 = mfma16(av1, bv1, a1);
    }
    f32x4 s = a0 + a1;
#pragma unroll
    for (int q = 0; q < 4; ++q) gt[w][lk * 4 + q][l16] = s[q];  // D: row=lk*4+q, col=l16
    // gt slice is wave-private: lgkmcnt is the only ordering needed
    asm volatile("s_waitcnt lgkmcnt(0)" ::: "memory");
    // ---- phase D: activations + h/c update (1 gate-set per lane) ----
    float f_ = gt[w][br2][rr] + bias_f;
    float i_ = gt[w][br2][4 + rr] + bias_i;
    float o_ = gt[w][br2][8 + rr] + bias_o;
    float g_ = gt[w][br2][12 + rr] + bias_c;
    cst = sigm(f_) * cst + sigm(i_) * tanh_f(g_);
    float hv = sigm(o_) * tanh_f(cst);
    const int hcol = n * HCPB + rr;
    // publish h: packed u32 agent-scope WT store (write-once slab, LLC authoritative)
    unsigned hb = (unsigned)__builtin_bit_cast(unsigned short, (__bf16)hv);
    unsigned nb = __shfl_down(hb, 1);
    if ((rr & 1) == 0) {
      unsigned pk = hb | (nb << 16);
      unsigned* dst = (unsigned*)(hsb + (size_t)(t + 1) * (BB * HH) + (size_t)absrow * HH + hcol);
      __hip_atomic_store(dst, pk, __ATOMIC_RELAXED, __HIP_MEMORY_SCOPE_AGENT);
    }
    if (t == SS - 1) {
      tail[(size_t)absrow * HH + hcol] = hv;
      tail[(size_t)BB * HH + (size_t)absrow * HH + hcol] = cst;
    }
    // ---- phase E: per-wave drain + per-wave flag. No barriers, no cross-wave wait. ----
    asm volatile("s_waitcnt vmcnt(0)" ::: "memory");
    if (t + 1 < SS && l == 0)
      __hip_atomic_store(&myflags[n], (unsigned)(t + 1), __ATOMIC_RELAXED,
                         __HIP_MEMORY_SCOPE_AGENT);
  }
}

// GEMM-2: out[r=b*S+t][col] = hs[t+1][b][:] . Wfc[col][:] + bfc[col]  (M=32768,N=512,K=1024)
__global__ __launch_bounds__(256) void k_gemm_out(const __bf16* __restrict__ hsb,
                                                  const __bf16* __restrict__ Wfcb,
                                                  const float* __restrict__ bfc,
                                                  float* __restrict__ out) {
  int w = threadIdx.x >> 6, l = threadIdx.x & 63;
  int l16 = l & 15, lk = l >> 4;
  int Mbase = blockIdx.x * 64, Nbase = blockIdx.y * 64;
  int rA = Mbase + w * 16 + l16;
  int bb = rA >> 9, tt = rA & 511;
  const __bf16* Ap = hsb + ((size_t)(tt + 1) * BB + bb) * HH + lk * 8;
  const __bf16* Bp[4];
#pragma unroll
  for (int jt = 0; jt < 4; ++jt)
    Bp[jt] = Wfcb + ((size_t)(Nbase + jt * 16 + l16)) * HH + lk * 8;
  const f32x4 vz = {0.f, 0.f, 0.f, 0.f};
  f32x4 acc[4] = {vz, vz, vz, vz};
  for (int kc = 0; kc < HH; kc += 32) {
    bf16x8 a = *(const bf16x8*)(Ap + kc);
#pragma unroll
    for (int jt = 0; jt < 4; ++jt) {
      bf16x8 bv = *(const bf16x8*)(Bp[jt] + kc);
      acc[jt] = mfma16(a, bv, acc[jt]);
    }
  }
#pragma unroll
  for (int jt = 0; jt < 4; ++jt) {
    int col = Nbase + jt * 16 + l16;
    float badd = bfc[col];
#pragma unroll
    for (int q = 0; q < 4; ++q) {
      int rD = Mbase + w * 16 + lk * 4 + q;
      out[(size_t)rD * OO + col] = acc[jt][q] + badd;
    }
  }
}

extern "C" void kernel_launch(void* const* d_in, const int* in_sizes, int n_in,
                              void* d_out, int out_size, void* d_ws, size_t ws_size,
                              hipStream_t stream) {
  const float* x = (const float*)d_in[0];
  const float* Wf = (const float*)d_in[1];
  const float* Wi = (const float*)d_in[2];
  const float* Wo = (const float*)d_in[3];
  const float* Wc = (const float*)d_in[4];
  const float* bfv = (const float*)d_in[5];
  const float* biv = (const float*)d_in[6];
  const float* bov = (const float*)d_in[7];
  const float* bcv = (const float*)d_in[8];
  const float* Wfc = (const float*)d_in[9];
  const float* bfc = (const float*)d_in[10];
  float* out = (float*)d_out;

  char* ws = (char*)d_ws;
  size_t off = 0;
  auto take = [&](size_t bytes) -> char* {
    off = (off + 255) & ~(size_t)255;
    char* p = ws + off;
    off += bytes;
    return p;
  };
  __bf16* Wcomb = (__bf16*)take((size_t)G4 * KK * 2);            // 12 MB
  __bf16* Wfcb = (__bf16*)take((size_t)OO * HH * 2);             // 1 MB
  float* biasp = (float*)take((size_t)G4 * 4);                   // 16 KB
  unsigned* flags = (unsigned*)take(4 * NBLK * 4);               // per-(group,block) flags, 4 KB
  __bf16* xb = (__bf16*)take((size_t)BB * SS * IN * 2);          // 32 MB
  __bf16* hsb = (__bf16*)take((size_t)(SS + 1) * BB * HH * 2);   // 64.1 MB
  if (off > ws_size) {
    hipLaunchKernelGGL(k_diag, dim3(1), dim3(1), 0, stream, out,
                       1.0e6f + (float)(ws_size >> 20));
    return;
  }

  hipMemsetAsync(flags, 0, 4 * NBLK * 4, stream);  // reset flags each launch (graph-safe)
  hipLaunchKernelGGL(k_convw, dim3(G4), dim3(256), 0, stream,
                     Wf, Wi, Wo, Wc, bfv, biv, bov, bcv, Wcomb, biasp);
  hipLaunchKernelGGL(k_convx, dim3((BB * SS * IN) / 256), dim3(256), 0, stream, x, xb);
  hipLaunchKernelGGL(k_convfc, dim3((OO * HH) / 256), dim3(256), 0, stream, Wfc, Wfcb);
  hipLaunchKernelGGL(k_zeroh0, dim3((BB * HH) / 256), dim3(256), 0, stream, hsb);

  float* tail = out + (size_t)BB * SS * OO;
  void* args[] = {(void*)&Wcomb, (void*)&xb, (void*)&biasp, (void*)&hsb,
                  (void*)&tail, (void*)&flags};
  hipError_t cerr = hipLaunchCooperativeKernel((const void*)k_lstm, dim3(NBLK), dim3(256),
                                               args, 0, stream);
  if (cerr != hipSuccess) {
    hipLaunchKernelGGL(k_diag, dim3(1), dim3(1), 0, stream, out,
                       1.0e5f + (float)(int)cerr);
    return;
  }

  hipLaunchKernelGGL(k_gemm_out, dim3((BB * SS) / 64, OO / 64), dim3(256), 0, stream,
                     hsb, Wfcb, bfc, out);
}

// Round 14
// 3666.330 us; speedup vs baseline: 1.9422x; 1.9422x over previous
//
#include <hip/hip_runtime.h>
#include <hip/hip_bf16.h>

typedef __attribute__((ext_vector_type(8))) __bf16 bf16x8;
typedef __attribute__((ext_vector_type(4))) float f32x4;

static constexpr int BB = 64;    // batch
static constexpr int SS = 512;   // seq len
static constexpr int IN = 512;   // input dim
static constexpr int HH = 1024;  // hidden
static constexpr int OO = 512;   // output dim
static constexpr int KK = 1536;  // H + I (combined recurrent K)
static constexpr int G4 = 4096;  // 4*H
static constexpr int NBLK = 512; // 2 recurrences x 256 col-blocks
static constexpr int THR = 128;  // 2 waves per block
static constexpr int COLS = 16;  // gate-cols per block
static constexpr int HCPB = 4;   // h-cols per block
static constexpr int RROWS = 32; // batch rows per recurrence

__device__ __forceinline__ f32x4 mfma16(bf16x8 a, bf16x8 b, f32x4 c) {
  return __builtin_amdgcn_mfma_f32_16x16x32_bf16(a, b, c, 0, 0, 0);
}
__device__ __forceinline__ float sigm(float x) { return 1.f / (1.f + __expf(-x)); }
__device__ __forceinline__ float tanh_f(float x) { return 1.f - 2.f / (1.f + __expf(2.f * x)); }

// Gate-col permutation: p = m*16 + g*4 + r  <->  gate g, hcol = m*4 + r.

__global__ void k_convw(const float* Wf, const float* Wi, const float* Wo, const float* Wc,
                        const float* bfv, const float* biv, const float* bov, const float* bcv,
                        __bf16* Wcomb, float* biasp) {
  int p = blockIdx.x;                       // 0..4095
  int g = (p >> 2) & 3;
  int hcol = ((p >> 4) << 2) | (p & 3);
  const float* Wg = (g == 0) ? Wf : (g == 1) ? Wi : (g == 2) ? Wo : Wc;
  const float* bg = (g == 0) ? bfv : (g == 1) ? biv : (g == 2) ? bov : bcv;
  const float* src = Wg + (size_t)hcol * KK;
  for (int k = threadIdx.x; k < KK; k += 256) Wcomb[(size_t)p * KK + k] = (__bf16)src[k];
  if (threadIdx.x == 0) biasp[p] = bg[hcol];
}

// xb[(t*64+b)*512 + k] = bf16(x[b][t][k])   (t-major rows for the recurrent A-fragments)
__global__ void k_convx(const float* x, __bf16* xb) {
  size_t idx = (size_t)blockIdx.x * 256 + threadIdx.x;  // 16,777,216
  int k = idx & 511;
  size_t row = idx >> 9;
  int t = (int)(row >> 6), b = (int)(row & 63);
  xb[idx] = (__bf16)x[((size_t)b * SS + t) * IN + k];
}

__global__ void k_convfc(const float* Wfc, __bf16* Wfcb) {
  size_t i = (size_t)blockIdx.x * 256 + threadIdx.x;  // 524,288
  Wfcb[i] = (__bf16)Wfc[i];
}

__global__ void k_zeroh0(__bf16* hsb) {
  size_t i = (size_t)blockIdx.x * 256 + threadIdx.x;  // 65,536 (slot 0 = h_{-1} = 0)
  hsb[i] = (__bf16)0.f;
}

__global__ void k_diag(float* out, float v) { out[0] = v; }

// Persistent recurrent kernel: 512 blocks x 128 thr = TWO INDEPENDENT RECURRENCES
// (batch rows 0..31 / 32..63), each the proven r8 lockstep machine over 256
// col-blocks. Blocks n and n+256 (one per recurrence) co-reside per CU: while one
// rec's blocks sit in the flag-wait, the other's waves issue compute -> the two
// serial handoff chains interleave and hide each other. Per-rec protocol is
// byte-equivalent to r8: WT agent h stores, per-block flags, all-lane poll,
// per-wave vmcnt drain, ONE (2-wave) barrier per step.
__global__ __launch_bounds__(128) void k_lstm(const __bf16* __restrict__ Wcomb,
                                              const __bf16* __restrict__ xb,
                                              const float* __restrict__ biasp,
                                              __bf16* __restrict__ hsb,
                                              float* __restrict__ tail,
                                              unsigned* __restrict__ flags) {
  const int n = blockIdx.x;
  const int R = n >> 8;            // recurrence id (0: rows 0..31, 1: rows 32..63)
  const int m = n & 255;           // col-block index within the recurrence
  const int tid = threadIdx.x;     // 0..127
  const int w = tid >> 6, l = tid & 63;
  const int l16 = l & 15, lk = l >> 4;
  __shared__ __bf16 wl[48 * 512];  // 48 chunks x (4 lk x 16 cols x 8) bf16 = 49,152 B
  __shared__ float gt[32][20];     // MFMA D spill: 32 rows (this rec), 2-way banks free
  // --- preload weight slice into LDS, fragment-major ---
  for (int i = tid; i < COLS * (KK / 8); i += THR) {  // 16*192 = 3072
    int c = i / 192, kch = i % 192;
    bf16x8 v = *(const bf16x8*)(Wcomb + ((size_t)(m * COLS + c)) * KK + kch * 8);
    int chunk = kch >> 2, lkw = kch & 3;
    *(bf16x8*)(wl + ((chunk * 64 + lkw * 16 + c) << 3)) = v;
  }
  const int br = tid >> 2, rr = tid & 3;  // row-in-rec 0..31 (wave-local), hcol offset
  const int arow = R * RROWS + br;        // absolute batch row
  const float bias_f = biasp[m * COLS + 0 + rr];
  const float bias_i = biasp[m * COLS + 4 + rr];
  const float bias_o = biasp[m * COLS + 8 + rr];
  const float bias_c = biasp[m * COLS + 12 + rr];
  __syncthreads();
  const size_t aoffH = (size_t)(R * RROWS + w * 16 + l16) * HH + lk * 8;
  const size_t aoffX = (size_t)(R * RROWS + w * 16 + l16) * IN + lk * 8;
  const __bf16* wlane = wl + ((lk * 16 + l16) << 3);
  const unsigned* myflags = flags + R * 256;  // this recurrence's 256 producer flags
  const int startC = (n >> 3) & 15;           // stagger key: co-XCD siblings differ
  const f32x4 vz = {0.f, 0.f, 0.f, 0.f};
  float cst = 0.f;
  for (int t = 0; t < SS; ++t) {
    const __bf16* hp = hsb + (size_t)t * (BB * HH);
    const __bf16* xp = xb + (size_t)t * (BB * IN);
    f32x4 a0 = vz, a1 = vz;
    // ---- phase A: x-part (no h dependency; overlaps the other rec + own-rec tail) ----
#pragma unroll
    for (int kc = 0; kc < IN; kc += 64) {   // x-part: chunks 32..47
      bf16x8 av0 = *(const bf16x8*)(xp + aoffX + kc);
      bf16x8 av1 = *(const bf16x8*)(xp + aoffX + kc + 32);
      bf16x8 bv0 = *(const bf16x8*)(wlane + (32 + kc / 32) * 512);
      bf16x8 bv1 = *(const bf16x8*)(wlane + (33 + kc / 32) * 512);
      a0 = mfma16(av0, bv0, a0);
      a1 = mfma16(av1, bv1, a1);
    }
    // ---- phase B: wait for this recurrence's 256 producers (each wave, 64-lane poll) ----
    {
      const unsigned tgt = (unsigned)t;
      for (;;) {
        unsigned f0 = __hip_atomic_load(&myflags[l * 4 + 0], __ATOMIC_RELAXED, __HIP_MEMORY_SCOPE_AGENT);
        unsigned f1 = __hip_atomic_load(&myflags[l * 4 + 1], __ATOMIC_RELAXED, __HIP_MEMORY_SCOPE_AGENT);
        unsigned f2 = __hip_atomic_load(&myflags[l * 4 + 2], __ATOMIC_RELAXED, __HIP_MEMORY_SCOPE_AGENT);
        unsigned f3 = __hip_atomic_load(&myflags[l * 4 + 3], __ATOMIC_RELAXED, __HIP_MEMORY_SCOPE_AGENT);
        bool ok = (f0 >= tgt) & (f1 >= tgt) & (f2 >= tgt) & (f3 >= tgt);
        if (__all((int)ok)) break;
        __builtin_amdgcn_s_sleep(1);
      }
    }
    asm volatile("" ::: "memory");  // no speculative h-load hoisting above the wait
    // ---- phase C: h-part (this rec's 32 rows; plain cached loads, L2-shared per XCD) ----
#pragma unroll
    for (int i = 0; i < 16; ++i) {
      int cc = (startC + i) & 15;       // 16 double-chunks of 64 k each
      int kc = cc * 64;
      bf16x8 av0 = *(const bf16x8*)(hp + aoffH + kc);
      bf16x8 av1 = *(const bf16x8*)(hp + aoffH + kc + 32);
      bf16x8 bv0 = *(const bf16x8*)(wlane + (cc * 2) * 512);
      bf16x8 bv1 = *(const bf16x8*)(wlane + (cc * 2 + 1) * 512);
      a0 = mfma16(av0, bv0, a0);
      a1 = mfma16(av1, bv1, a1);
    }
    f32x4 s = a0 + a1;
#pragma unroll
    for (int q = 0; q < 4; ++q) gt[w * 16 + lk * 4 + q][l16] = s[q];  // D: row=lk*4+q, col=l16
    // gt exchange is wave-local: wave w writes rows [16w,16w+16); act thread br=tid>>2
    // reads row br with br>>4 == tid>>6 (same wave) -> lgkmcnt suffices.
    asm volatile("s_waitcnt lgkmcnt(0)" ::: "memory");
    // ---- phase D: activations + h/c update (1 gate-set per thread) ----
    float f_ = gt[br][rr] + bias_f;
    float i_ = gt[br][4 + rr] + bias_i;
    float o_ = gt[br][8 + rr] + bias_o;
    float g_ = gt[br][12 + rr] + bias_c;
    cst = sigm(f_) * cst + sigm(i_) * tanh_f(g_);
    float hv = sigm(o_) * tanh_f(cst);
    const int hcol = m * HCPB + rr;
    // publish h: packed u32 agent-scope WT store (write-once slab, LLC authoritative)
    unsigned hb = (unsigned)__builtin_bit_cast(unsigned short, (__bf16)hv);
    unsigned nb = __shfl_down(hb, 1);
    if ((rr & 1) == 0) {
      unsigned pk = hb | (nb << 16);
      unsigned* dst = (unsigned*)(hsb + (size_t)(t + 1) * (BB * HH) + (size_t)arow * HH + hcol);
      __hip_atomic_store(dst, pk, __ATOMIC_RELAXED, __HIP_MEMORY_SCOPE_AGENT);
    }
    if (t == SS - 1) {
      tail[(size_t)arow * HH + hcol] = hv;
      tail[(size_t)BB * HH + (size_t)arow * HH + hcol] = cst;
    }
    // ---- phase E: per-wave drain, one 2-wave barrier, then this block's flag ----
    asm volatile("s_waitcnt vmcnt(0)" ::: "memory");
    __syncthreads();
    if (t + 1 < SS && tid == 0)
      __hip_atomic_store((unsigned*)&flags[n], (unsigned)(t + 1), __ATOMIC_RELAXED,
                         __HIP_MEMORY_SCOPE_AGENT);
  }
}

// GEMM-2: out[r=b*S+t][col] = hs[t+1][b][:] . Wfc[col][:] + bfc[col]  (M=32768,N=512,K=1024)
__global__ __launch_bounds__(256) void k_gemm_out(const __bf16* __restrict__ hsb,
                                                  const __bf16* __restrict__ Wfcb,
                                                  const float* __restrict__ bfc,
                                                  float* __restrict__ out) {
  int w = threadIdx.x >> 6, l = threadIdx.x & 63;
  int l16 = l & 15, lk = l >> 4;
  int Mbase = blockIdx.x * 64, Nbase = blockIdx.y * 64;
  int rA = Mbase + w * 16 + l16;
  int bb = rA >> 9, tt = rA & 511;
  const __bf16* Ap = hsb + ((size_t)(tt + 1) * BB + bb) * HH + lk * 8;
  const __bf16* Bp[4];
#pragma unroll
  for (int jt = 0; jt < 4; ++jt)
    Bp[jt] = Wfcb + ((size_t)(Nbase + jt * 16 + l16)) * HH + lk * 8;
  const f32x4 vz = {0.f, 0.f, 0.f, 0.f};
  f32x4 acc[4] = {vz, vz, vz, vz};
  for (int kc = 0; kc < HH; kc += 32) {
    bf16x8 a = *(const bf16x8*)(Ap + kc);
#pragma unroll
    for (int jt = 0; jt < 4; ++jt) {
      bf16x8 bv = *(const bf16x8*)(Bp[jt] + kc);
      acc[jt] = mfma16(a, bv, acc[jt]);
    }
  }
#pragma unroll
  for (int jt = 0; jt < 4; ++jt) {
    int col = Nbase + jt * 16 + l16;
    float badd = bfc[col];
#pragma unroll
    for (int q = 0; q < 4; ++q) {
      int rD = Mbase + w * 16 + lk * 4 + q;
      out[(size_t)rD * OO + col] = acc[jt][q] + badd;
    }
  }
}

extern "C" void kernel_launch(void* const* d_in, const int* in_sizes, int n_in,
                              void* d_out, int out_size, void* d_ws, size_t ws_size,
                              hipStream_t stream) {
  const float* x = (const float*)d_in[0];
  const float* Wf = (const float*)d_in[1];
  const float* Wi = (const float*)d_in[2];
  const float* Wo = (const float*)d_in[3];
  const float* Wc = (const float*)d_in[4];
  const float* bfv = (const float*)d_in[5];
  const float* biv = (const float*)d_in[6];
  const float* bov = (const float*)d_in[7];
  const float* bcv = (const float*)d_in[8];
  const float* Wfc = (const float*)d_in[9];
  const float* bfc = (const float*)d_in[10];
  float* out = (float*)d_out;

  char* ws = (char*)d_ws;
  size_t off = 0;
  auto take = [&](size_t bytes) -> char* {
    off = (off + 255) & ~(size_t)255;
    char* p = ws + off;
    off += bytes;
    return p;
  };
  __bf16* Wcomb = (__bf16*)take((size_t)G4 * KK * 2);            // 12 MB
  __bf16* Wfcb = (__bf16*)take((size_t)OO * HH * 2);             // 1 MB
  float* biasp = (float*)take((size_t)G4 * 4);                   // 16 KB
  unsigned* flags = (unsigned*)take(NBLK * 4);                   // per-block flags (2 KB)
  __bf16* xb = (__bf16*)take((size_t)BB * SS * IN * 2);          // 32 MB
  __bf16* hsb = (__bf16*)take((size_t)(SS + 1) * BB * HH * 2);   // 64.1 MB
  if (off > ws_size) {
    hipLaunchKernelGGL(k_diag, dim3(1), dim3(1), 0, stream, out,
                       1.0e6f + (float)(ws_size >> 20));
    return;
  }

  hipMemsetAsync(flags, 0, NBLK * 4, stream);  // reset flags each launch (graph-safe)
  hipLaunchKernelGGL(k_convw, dim3(G4), dim3(256), 0, stream,
                     Wf, Wi, Wo, Wc, bfv, biv, bov, bcv, Wcomb, biasp);
  hipLaunchKernelGGL(k_convx, dim3((BB * SS * IN) / 256), dim3(256), 0, stream, x, xb);
  hipLaunchKernelGGL(k_convfc, dim3((OO * HH) / 256), dim3(256), 0, stream, Wfc, Wfcb);
  hipLaunchKernelGGL(k_zeroh0, dim3((BB * HH) / 256), dim3(256), 0, stream, hsb);

  float* tail = out + (size_t)BB * SS * OO;
  void* args[] = {(void*)&Wcomb, (void*)&xb, (void*)&biasp, (void*)&hsb,
                  (void*)&tail, (void*)&flags};
  hipError_t cerr = hipLaunchCooperativeKernel((const void*)k_lstm, dim3(NBLK), dim3(THR),
                                               args, 0, stream);
  if (cerr != hipSuccess) {
    hipLaunchKernelGGL(k_diag, dim3(1), dim3(1), 0, stream, out,
                       1.0e5f + (float)(int)cerr);
    return;
  }

  hipLaunchKernelGGL(k_gemm_out, dim3((BB * SS) / 64, OO / 64), dim3(256), 0, stream,
                     hsb, Wfcb, bfc, out);
}

// Round 15
// 2898.628 us; speedup vs baseline: 2.4566x; 1.2649x over previous
//
#include <hip/hip_runtime.h>
#include <hip/hip_bf16.h>

typedef __attribute__((ext_vector_type(8))) __bf16 bf16x8;
typedef __attribute__((ext_vector_type(4))) float f32x4;
typedef __attribute__((ext_vector_type(4))) unsigned uint4v;
typedef unsigned long long u64;

static constexpr int BB = 64;    // batch
static constexpr int SS = 512;   // seq len
static constexpr int IN = 512;   // input dim
static constexpr int HH = 1024;  // hidden
static constexpr int OO = 512;   // output dim
static constexpr int KK = 1536;  // H + I (combined recurrent K)
static constexpr int G4 = 4096;  // 4*H
static constexpr int NBLK = 512; // 2 recurrences x 256 col-blocks
static constexpr int THR = 128;  // 2 waves per block
static constexpr int COLS = 16;  // gate-cols per block
static constexpr int HCPB = 4;   // h-cols per block
static constexpr int RROWS = 32; // batch rows per recurrence
// h storage (permuted, producer-owned): elem idx = t*65536 + (R*256+m)*128 + row*4 + rr
// (k = m*4+rr is the NATURAL h-col order, so weight layout is unchanged)
static constexpr size_t SLAB_B = (size_t)BB * HH * 2;  // 131072 bytes per t-slab

__device__ __forceinline__ f32x4 mfma16(bf16x8 a, bf16x8 b, f32x4 c) {
  return __builtin_amdgcn_mfma_f32_16x16x32_bf16(a, b, c, 0, 0, 0);
}
__device__ __forceinline__ float sigm(float x) { return 1.f / (1.f + __expf(-x)); }
__device__ __forceinline__ float tanh_f(float x) { return 1.f - 2.f / (1.f + __expf(2.f * x)); }
__device__ __forceinline__ bf16x8 frag2(const char* p0) {
  u64 lo = *(const u64*)p0;
  u64 hi = *(const u64*)(p0 + 256);
  uint4v u;
  u[0] = (unsigned)lo; u[1] = (unsigned)(lo >> 32);
  u[2] = (unsigned)hi; u[3] = (unsigned)(hi >> 32);
  return __builtin_bit_cast(bf16x8, u);
}

// Gate-col permutation: p = m*16 + g*4 + r  <->  gate g, hcol = m*4 + r.

__global__ void k_convw(const float* Wf, const float* Wi, const float* Wo, const float* Wc,
                        const float* bfv, const float* biv, const float* bov, const float* bcv,
                        __bf16* Wcomb, float* biasp) {
  int p = blockIdx.x;                       // 0..4095
  int g = (p >> 2) & 3;
  int hcol = ((p >> 4) << 2) | (p & 3);
  const float* Wg = (g == 0) ? Wf : (g == 1) ? Wi : (g == 2) ? Wo : Wc;
  const float* bg = (g == 0) ? bfv : (g == 1) ? biv : (g == 2) ? bov : bcv;
  const float* src = Wg + (size_t)hcol * KK;
  for (int k = threadIdx.x; k < KK; k += 256) Wcomb[(size_t)p * KK + k] = (__bf16)src[k];
  if (threadIdx.x == 0) biasp[p] = bg[hcol];
}

// xb[(t*64+b)*512 + k] = bf16(x[b][t][k])
__global__ void k_convx(const float* x, __bf16* xb) {
  size_t idx = (size_t)blockIdx.x * 256 + threadIdx.x;  // 16,777,216
  int k = idx & 511;
  size_t row = idx >> 9;
  int t = (int)(row >> 6), b = (int)(row & 63);
  xb[idx] = (__bf16)x[((size_t)b * SS + t) * IN + k];
}

__global__ void k_convfc(const float* Wfc, __bf16* Wfcb) {
  size_t i = (size_t)blockIdx.x * 256 + threadIdx.x;  // 524,288
  Wfcb[i] = (__bf16)Wfc[i];
}

__global__ void k_zeroh0(__bf16* hsb) {
  size_t i = (size_t)blockIdx.x * 256 + threadIdx.x;  // 65,536 (slot 0 = h_{-1} = 0)
  hsb[i] = (__bf16)0.f;
}

__global__ void k_diag(float* out, float v) { out[0] = v; }

// Persistent recurrent kernel: 512 blocks x 128 thr (r14 structure) + PERMUTED
// PRODUCER-OWNED h LAYOUT: block (R,m)'s 4 h-cols x 32 rows live in ONE contiguous
// 256B region; each wave publishes 16 x 8B = 128B whole-sector agent stores.
// This removes the partial-sector write-through RMW that amplified WRITE 4x and
// FETCH 6x (r14 counters) and sat at the head of the per-step visibility chain.
__global__ __launch_bounds__(128) void k_lstm(const __bf16* __restrict__ Wcomb,
                                              const __bf16* __restrict__ xb,
                                              const float* __restrict__ biasp,
                                              __bf16* __restrict__ hsb,
                                              float* __restrict__ tail,
                                              unsigned* __restrict__ flags) {
  const int n = blockIdx.x;
  const int R = n >> 8;            // recurrence id (0: rows 0..31, 1: rows 32..63)
  const int m = n & 255;           // col-block index within the recurrence
  const int tid = threadIdx.x;     // 0..127
  const int w = tid >> 6, l = tid & 63;
  const int l16 = l & 15, lk = l >> 4;
  __shared__ __bf16 wl[48 * 512];  // 48 chunks x (4 lk x 16 cols x 8) bf16 = 49,152 B
  __shared__ float gt[32][20];     // MFMA D spill: 32 rows (this rec), 2-way banks free
  // --- preload weight slice into LDS, fragment-major ---
  for (int i = tid; i < COLS * (KK / 8); i += THR) {  // 16*192 = 3072
    int c = i / 192, kch = i % 192;
    bf16x8 v = *(const bf16x8*)(Wcomb + ((size_t)(m * COLS + c)) * KK + kch * 8);
    int chunk = kch >> 2, lkw = kch & 3;
    *(bf16x8*)(wl + ((chunk * 64 + lkw * 16 + c) << 3)) = v;
  }
  const int br = tid >> 2, rr = tid & 3;  // row-in-rec 0..31 (wave-local), hcol offset
  const int arow = R * RROWS + br;        // absolute batch row
  const float bias_f = biasp[m * COLS + 0 + rr];
  const float bias_i = biasp[m * COLS + 4 + rr];
  const float bias_o = biasp[m * COLS + 8 + rr];
  const float bias_c = biasp[m * COLS + 12 + rr];
  __syncthreads();
  const int hrow = w * 16 + l16;          // this lane's A-fragment row (within rec)
  const size_t aoffX = (size_t)(R * RROWS + hrow) * IN + lk * 8;
  const __bf16* wlane = wl + ((lk * 16 + l16) << 3);
  const unsigned* myflags = flags + R * 256;  // this recurrence's 256 producer flags
  const int startC = (n >> 3) & 15;           // stagger key: co-XCD siblings differ
  const f32x4 vz = {0.f, 0.f, 0.f, 0.f};
  float cst = 0.f;
  for (int t = 0; t < SS; ++t) {
    // permuted h base for this rec at step t, plus this lane's (lk,row) offset
    const char* hpb = (const char*)hsb + (size_t)t * SLAB_B + (size_t)R * 65536
                      + (size_t)lk * 512 + (size_t)hrow * 8;
    const __bf16* xp = xb + (size_t)t * (BB * IN);
    f32x4 a0 = vz, a1 = vz;
    // ---- phase A: x-part (no h dependency) ----
#pragma unroll
    for (int kc = 0; kc < IN; kc += 64) {   // x-part: chunks 32..47
      bf16x8 av0 = *(const bf16x8*)(xp + aoffX + kc);
      bf16x8 av1 = *(const bf16x8*)(xp + aoffX + kc + 32);
      bf16x8 bv0 = *(const bf16x8*)(wlane + (32 + kc / 32) * 512);
      bf16x8 bv1 = *(const bf16x8*)(wlane + (33 + kc / 32) * 512);
      a0 = mfma16(av0, bv0, a0);
      a1 = mfma16(av1, bv1, a1);
    }
    // ---- phase B: wait for this recurrence's 256 producers (64-lane poll) ----
    {
      const unsigned tgt = (unsigned)t;
      for (;;) {
        unsigned f0 = __hip_atomic_load(&myflags[l * 4 + 0], __ATOMIC_RELAXED, __HIP_MEMORY_SCOPE_AGENT);
        unsigned f1 = __hip_atomic_load(&myflags[l * 4 + 1], __ATOMIC_RELAXED, __HIP_MEMORY_SCOPE_AGENT);
        unsigned f2 = __hip_atomic_load(&myflags[l * 4 + 2], __ATOMIC_RELAXED, __HIP_MEMORY_SCOPE_AGENT);
        unsigned f3 = __hip_atomic_load(&myflags[l * 4 + 3], __ATOMIC_RELAXED, __HIP_MEMORY_SCOPE_AGENT);
        bool ok = (f0 >= tgt) & (f1 >= tgt) & (f2 >= tgt) & (f3 >= tgt);
        if (__all((int)ok)) break;
        __builtin_amdgcn_s_sleep(1);
      }
    }
    asm volatile("" ::: "memory");  // no speculative h-load hoisting above the wait
    // ---- phase C: h-part; fragment = two 8B loads 256B apart (chunk cc covers
    //      producer blocks m0=cc*8+lk*2 and m0+1; k-order = natural h-cols) ----
#pragma unroll
    for (int i = 0; i < 16; ++i) {
      int cc = (startC + i) & 15;       // 16 double-chunks of 64 k each
      const char* pc = hpb + (size_t)cc * 4096;      // 2 chunks x 2048B each
      bf16x8 av0 = frag2(pc);                        // chunk 2cc   (m0 = cc*16+lk*2... see map)
      bf16x8 av1 = frag2(pc + 2048);                 // chunk 2cc+1
      bf16x8 bv0 = *(const bf16x8*)(wlane + (cc * 2) * 512);
      bf16x8 bv1 = *(const bf16x8*)(wlane + (cc * 2 + 1) * 512);
      a0 = mfma16(av0, bv0, a0);
      a1 = mfma16(av1, bv1, a1);
    }
    f32x4 s = a0 + a1;
#pragma unroll
    for (int q = 0; q < 4; ++q) gt[w * 16 + lk * 4 + q][l16] = s[q];  // D: row=lk*4+q, col=l16
    asm volatile("s_waitcnt lgkmcnt(0)" ::: "memory");  // gt exchange is wave-local
    // ---- phase D: activations + h/c update (1 gate-set per thread) ----
    float f_ = gt[br][rr] + bias_f;
    float i_ = gt[br][4 + rr] + bias_i;
    float o_ = gt[br][8 + rr] + bias_o;
    float g_ = gt[br][12 + rr] + bias_c;
    cst = sigm(f_) * cst + sigm(i_) * tanh_f(g_);
    float hv = sigm(o_) * tanh_f(cst);
    // publish h: pack 4 cols (rr=0..3) into one u64; 16 lanes/wave x 8B = 128B
    // contiguous whole-sector agent store into this block's OWN 256B region.
    unsigned hb = (unsigned)__builtin_bit_cast(unsigned short, (__bf16)hv);
    unsigned h1 = __shfl_down(hb, 1);
    unsigned h2 = __shfl_down(hb, 2);
    unsigned h3 = __shfl_down(hb, 3);
    if (rr == 0) {
      u64 pk = (u64)hb | ((u64)h1 << 16) | ((u64)h2 << 32) | ((u64)h3 << 48);
      u64* dst = (u64*)((char*)hsb + (size_t)(t + 1) * SLAB_B
                        + (size_t)(R * 256 + m) * 256 + (size_t)br * 8);
      __hip_atomic_store(dst, pk, __ATOMIC_RELAXED, __HIP_MEMORY_SCOPE_AGENT);
    }
    if (t == SS - 1) {
      tail[(size_t)arow * HH + m * HCPB + rr] = hv;
      tail[(size_t)BB * HH + (size_t)arow * HH + m * HCPB + rr] = cst;
    }
    // ---- phase E: per-wave drain, one 2-wave barrier, then this block's flag ----
    asm volatile("s_waitcnt vmcnt(0)" ::: "memory");
    __syncthreads();
    if (t + 1 < SS && tid == 0)
      __hip_atomic_store((unsigned*)&flags[n], (unsigned)(t + 1), __ATOMIC_RELAXED,
                         __HIP_MEMORY_SCOPE_AGENT);
  }
}

// GEMM-2: out[r=b*S+t][col] = h[t+1][b][:] . Wfc[col][:] + bfc[col]  (M=32768,N=512,K=1024)
// A reads the permuted h layout: k-chunk at kc+lk*8 -> producer blocks kc/4+lk*2, +1.
__global__ __launch_bounds__(256) void k_gemm_out(const __bf16* __restrict__ hsb,
                                                  const __bf16* __restrict__ Wfcb,
                                                  const float* __restrict__ bfc,
                                                  float* __restrict__ out) {
  int w = threadIdx.x >> 6, l = threadIdx.x & 63;
  int l16 = l & 15, lk = l >> 4;
  int Mbase = blockIdx.x * 64, Nbase = blockIdx.y * 64;
  int rA = Mbase + w * 16 + l16;
  int bb = rA >> 9, tt = rA & 511;
  const char* Apb = (const char*)hsb + (size_t)(tt + 1) * SLAB_B + (size_t)(bb >> 5) * 65536
                    + (size_t)(bb & 31) * 8 + (size_t)lk * 512;
  const __bf16* Bp[4];
#pragma unroll
  for (int jt = 0; jt < 4; ++jt)
    Bp[jt] = Wfcb + ((size_t)(Nbase + jt * 16 + l16)) * HH + lk * 8;
  const f32x4 vz = {0.f, 0.f, 0.f, 0.f};
  f32x4 acc[4] = {vz, vz, vz, vz};
  for (int kc = 0; kc < HH; kc += 32) {
    bf16x8 a = frag2(Apb + (size_t)kc * 64);
#pragma unroll
    for (int jt = 0; jt < 4; ++jt) {
      bf16x8 bv = *(const bf16x8*)(Bp[jt] + kc);
      acc[jt] = mfma16(a, bv, acc[jt]);
    }
  }
#pragma unroll
  for (int jt = 0; jt < 4; ++jt) {
    int col = Nbase + jt * 16 + l16;
    float badd = bfc[col];
#pragma unroll
    for (int q = 0; q < 4; ++q) {
      int rD = Mbase + w * 16 + lk * 4 + q;
      out[(size_t)rD * OO + col] = acc[jt][q] + badd;
    }
  }
}

extern "C" void kernel_launch(void* const* d_in, const int* in_sizes, int n_in,
                              void* d_out, int out_size, void* d_ws, size_t ws_size,
                              hipStream_t stream) {
  const float* x = (const float*)d_in[0];
  const float* Wf = (const float*)d_in[1];
  const float* Wi = (const float*)d_in[2];
  const float* Wo = (const float*)d_in[3];
  const float* Wc = (const float*)d_in[4];
  const float* bfv = (const float*)d_in[5];
  const float* biv = (const float*)d_in[6];
  const float* bov = (const float*)d_in[7];
  const float* bcv = (const float*)d_in[8];
  const float* Wfc = (const float*)d_in[9];
  const float* bfc = (const float*)d_in[10];
  float* out = (float*)d_out;

  char* ws = (char*)d_ws;
  size_t off = 0;
  auto take = [&](size_t bytes) -> char* {
    off = (off + 255) & ~(size_t)255;
    char* p = ws + off;
    off += bytes;
    return p;
  };
  __bf16* Wcomb = (__bf16*)take((size_t)G4 * KK * 2);            // 12 MB
  __bf16* Wfcb = (__bf16*)take((size_t)OO * HH * 2);             // 1 MB
  float* biasp = (float*)take((size_t)G4 * 4);                   // 16 KB
  unsigned* flags = (unsigned*)take(NBLK * 4);                   // per-block flags (2 KB)
  __bf16* xb = (__bf16*)take((size_t)BB * SS * IN * 2);          // 32 MB
  __bf16* hsb = (__bf16*)take((size_t)(SS + 1) * BB * HH * 2);   // 64.1 MB
  if (off > ws_size) {
    hipLaunchKernelGGL(k_diag, dim3(1), dim3(1), 0, stream, out,
                       1.0e6f + (float)(ws_size >> 20));
    return;
  }

  hipMemsetAsync(flags, 0, NBLK * 4, stream);  // reset flags each launch (graph-safe)
  hipLaunchKernelGGL(k_convw, dim3(G4), dim3(256), 0, stream,
                     Wf, Wi, Wo, Wc, bfv, biv, bov, bcv, Wcomb, biasp);
  hipLaunchKernelGGL(k_convx, dim3((BB * SS * IN) / 256), dim3(256), 0, stream, x, xb);
  hipLaunchKernelGGL(k_convfc, dim3((OO * HH) / 256), dim3(256), 0, stream, Wfc, Wfcb);
  hipLaunchKernelGGL(k_zeroh0, dim3((BB * HH) / 256), dim3(256), 0, stream, hsb);

  float* tail = out + (size_t)BB * SS * OO;
  void* args[] = {(void*)&Wcomb, (void*)&xb, (void*)&biasp, (void*)&hsb,
                  (void*)&tail, (void*)&flags};
  hipError_t cerr = hipLaunchCooperativeKernel((const void*)k_lstm, dim3(NBLK), dim3(THR),
                                               args, 0, stream);
  if (cerr != hipSuccess) {
    hipLaunchKernelGGL(k_diag, dim3(1), dim3(1), 0, stream, out,
                       1.0e5f + (float)(int)cerr);
    return;
  }

  hipLaunchKernelGGL(k_gemm_out, dim3((BB * SS) / 64, OO / 64), dim3(256), 0, stream,
                     hsb, Wfcb, bfc, out);
}